// Round 20
// baseline (148.909 us; speedup 1.0000x reference)
//
#include <hip/hip_runtime.h>

// GCN forward, round 20: r19 + bigger segments (SEG=12288) in the binning
// pass, enabled by wave-cooperative per-bin run copy (drops the bslot table
// and its serial fill). Mean (block,bin) run 20 -> 31 codes (~2 lines),
// further cutting partial-line RMW on the bin-major stream-out.
//
//   dis[n] = rsqrt(deg_in[n] + 1)
//   layer1: aggx[n] = sx[n] + sum_{s->n} sx[s],  sx = (x*dis) fp16 [8-padded]
//           h1[n]   = lrelu(dis[n]*(aggx[n] @ W1) + b1)   [64] (LDS only)
//   layer2: t2[n]   = dis[n]*(h1[n] @ W2)  fp16            [32]
//           h2[n]   = lrelu(dis[n]*(t2[n] + sum t2[s]) + b2)
//   pool:   gsum[batch[n]] += h2[n];  out = (gsum/cnt) @ Wlin + blin

#define N_NODES 100000
#define N_EDGES 3200000
#define N_GRAPHS 1024
#define IN_F 6
#define H1 64
#define H2 32
#define SLOPE 0.01f

#define NBIN 400             // bins of 250 dst nodes
#define BIN_N 250
#define CAP2 8704            // per-bin edge capacity (8000 avg + ~8 sigma)
#define CAP2R 10752          // per-bin padded CSR window

#define SEG 12288            // edges per k_bin400 block
#define NSEGB ((N_EDGES + SEG - 1) / SEG)   // 261

typedef _Float16 f16;
typedef _Float16 h2 __attribute__((ext_vector_type(2)));
typedef int  iv4 __attribute__((ext_vector_type(4)));

static __device__ __forceinline__ float lrelu(float v) {
    return v > 0.0f ? v : SLOPE * v;
}

static __device__ __forceinline__ h2 uph(unsigned w) {
    union { unsigned u; h2 h; } cv; cv.u = w;
    return cv.h;
}

// ---- init: zero gsum/gcnt, bin cursors, zero rows ----
__global__ void k_init(float* __restrict__ gz, int* __restrict__ bz,
                       f16* __restrict__ t2z, f16* __restrict__ sxz) {
    int i = blockIdx.x * blockDim.x + threadIdx.x;
    if (i < N_GRAPHS * H2 + N_GRAPHS) gz[i] = 0.0f;
    if (i < NBIN + 16) bz[i] = 0;
    if (i < H2) t2z[i] = (f16)0.0f;
    if (i < 8) sxz[i] = (f16)0.0f;
}

// ---- single-pass 400-bin counting sort of the edge list.
// LDS staging; stream-out = wave-cooperative per-bin run copy (runs are
// contiguous in LDS and in global; lane-uniform metadata broadcasts). ----
__global__ void k_bin400(const int* __restrict__ src, const int* __restrict__ dst,
                         int* __restrict__ bcur2, unsigned* __restrict__ benc2) {
    __shared__ int hist[NBIN];
    __shared__ int lscan[NBIN];
    __shared__ int lcur[NBIN];
    __shared__ int gbase[NBIN];
    __shared__ int scn[512];
    __shared__ unsigned codes[SEG];          // 48 KB
    int tid = threadIdx.x;
    for (int i = tid; i < NBIN; i += 256) hist[i] = 0;
    __syncthreads();
    int e0 = blockIdx.x * SEG;
    int e1 = e0 + SEG; if (e1 > N_EDGES) e1 = N_EDGES;
    const iv4* d4 = (const iv4*)dst;
    const iv4* s4 = (const iv4*)src;
    int i40 = e0 >> 2, i41 = e1 >> 2;
    // phase 1: histogram
    for (int i4 = i40 + tid; i4 < i41; i4 += 256) {
        iv4 v = __builtin_nontemporal_load(d4 + i4);
        atomicAdd(&hist[v.x / BIN_N], 1);
        atomicAdd(&hist[v.y / BIN_N], 1);
        atomicAdd(&hist[v.z / BIN_N], 1);
        atomicAdd(&hist[v.w / BIN_N], 1);
    }
    __syncthreads();
    // phase 2: scan 400 (padded to 512), reserve global space
    scn[tid]       = (tid < NBIN) ? hist[tid] : 0;
    scn[tid + 256] = (tid + 256 < NBIN) ? hist[tid + 256] : 0;
    __syncthreads();
    for (int off = 1; off < 512; off <<= 1) {
        int v0 = (tid >= off) ? scn[tid - off] : 0;
        int v1 = (tid + 256 >= off) ? scn[tid + 256 - off] : 0;
        __syncthreads();
        scn[tid] += v0;
        scn[tid + 256] += v1;
        __syncthreads();
    }
    if (tid < NBIN) {
        int h = hist[tid];
        int ls = scn[tid] - h;          // exclusive
        lscan[tid] = ls;
        lcur[tid] = ls;
        gbase[tid] = h ? atomicAdd(&bcur2[tid], h) : 0;
    }
    if (tid + 256 < NBIN) {
        int t = tid + 256;
        int h = hist[t];
        int ls = scn[t] - h;
        lscan[t] = ls;
        lcur[t] = ls;
        gbase[t] = h ? atomicAdd(&bcur2[t], h) : 0;
    }
    __syncthreads();
    // phase 3: scatter codes (src<<8 | dst_local) into LDS runs
    for (int i4 = i40 + tid; i4 < i41; i4 += 256) {
        iv4 dv = __builtin_nontemporal_load(d4 + i4);
        iv4 sv = __builtin_nontemporal_load(s4 + i4);
        int b, p;
        b = dv.x / BIN_N; p = atomicAdd(&lcur[b], 1);
        codes[p] = ((unsigned)sv.x << 8) | (unsigned)(dv.x - b * BIN_N);
        b = dv.y / BIN_N; p = atomicAdd(&lcur[b], 1);
        codes[p] = ((unsigned)sv.y << 8) | (unsigned)(dv.y - b * BIN_N);
        b = dv.z / BIN_N; p = atomicAdd(&lcur[b], 1);
        codes[p] = ((unsigned)sv.z << 8) | (unsigned)(dv.z - b * BIN_N);
        b = dv.w / BIN_N; p = atomicAdd(&lcur[b], 1);
        codes[p] = ((unsigned)sv.w << 8) | (unsigned)(dv.w - b * BIN_N);
    }
    __syncthreads();
    // phase 4: wave-cooperative per-bin run copy (LDS-contig -> global-contig)
    int wave = tid >> 6;        // 0..3
    int lane = tid & 63;
    for (int b = wave; b < NBIN; b += 4) {
        int h = hist[b];
        if (!h) continue;
        int ls = lscan[b];
        long long gb = (long long)b * CAP2 + gbase[b];
        for (int j = lane; j < h; j += 64)
            benc2[gb + j] = codes[ls + j];
    }
}

// ---- per-bin LDS counting sort -> windowed CSR + deg/dis/sx ----
__global__ void k_sort(const unsigned* __restrict__ benc2, const int* __restrict__ bcur2,
                       const float* __restrict__ x,
                       int* __restrict__ csr, int* __restrict__ obeg, int* __restrict__ oend,
                       float* __restrict__ dis, f16* __restrict__ sx) {
    __shared__ int hist[256];
    __shared__ int scn[256];
    __shared__ int lcur[256];
    int bin = blockIdx.x;
    int tid = threadIdx.x;
    hist[tid] = 0;
    __syncthreads();
    int cnt = bcur2[bin];
    const unsigned* p = benc2 + (long long)bin * CAP2;
    for (int i = tid; i < cnt; i += 256)
        atomicAdd(&hist[p[i] & 0xFFu], 1);
    __syncthreads();
    int deg = hist[tid];
    int pad = (deg + 7) & ~7;
    scn[tid] = pad;
    __syncthreads();
    for (int off = 1; off < 256; off <<= 1) {
        int v = 0;
        if (tid >= off) v = scn[tid - off];
        __syncthreads();
        if (tid >= off) scn[tid] += v;
        __syncthreads();
    }
    int excl = scn[tid] - pad;               // exclusive scan of padded degs
    int gbase = bin * CAP2R;
    lcur[tid] = gbase + excl;
    if (tid < BIN_N) {
        int n = bin * BIN_N + tid;
        obeg[n] = gbase + excl;
        oend[n] = gbase + excl + pad;
        float dn = rsqrtf((float)(deg + 1));
        dis[n] = dn;
#pragma unroll
        for (int j = 0; j < IN_F; ++j)
            sx[n * 8 + j] = (f16)(x[n * IN_F + j] * dn);
        sx[n * 8 + 6] = (f16)0.0f;
        sx[n * 8 + 7] = (f16)0.0f;
    }
    __syncthreads();
    for (int i = tid; i < cnt; i += 256) {
        unsigned c = p[i];
        int pos = atomicAdd(&lcur[c & 0xFFu], 1);
        csr[pos] = (int)(c >> 8);
    }
    __syncthreads();
    if (tid < BIN_N) {
        int end = gbase + excl + pad;
        for (int j = lcur[tid]; j < end; ++j) csr[j] = N_NODES;   // zero-row pad
    }
}

// ---- fused layer 1: gather(sx dwords, fp16x2 accum) -> h1 (LDS) -> t2 ----
// 64 nodes/block, 4 lanes/node; each lane owns one dword (2 fp16 feats).
__global__ void k_l1(const unsigned* __restrict__ sxu, const int* __restrict__ obeg,
                     const int* __restrict__ oend, const int* __restrict__ csr,
                     const float* __restrict__ W1, const float* __restrict__ b1,
                     const float* __restrict__ W2, const float* __restrict__ dis,
                     f16* __restrict__ t2) {
    __shared__ float sW1[IN_F * H1];
    __shared__ float sb1[H1];
    __shared__ float sW2[H1 * H2];
    __shared__ float sagg[64][9];       // +pad
    __shared__ float sh1[64][H1 + 1];   // +pad
    __shared__ float sdis[64];
    int tid = threadIdx.x;
    for (int i = tid; i < IN_F * H1; i += 256) sW1[i] = W1[i];
    if (tid < H1) sb1[tid] = b1[tid];
    for (int i = tid; i < H1 * H2; i += 256) sW2[i] = W2[i];
    int loc = tid >> 2;        // 0..63
    int f = tid & 3;           // dword index within 16B row
    int n = blockIdx.x * 64 + loc;
    bool ok = n < N_NODES;
    if (ok) {
        h2 acc = uph(sxu[(n << 2) + f]);
        int b = obeg[n], e = oend[n];
        for (int j = b; j < e; j += 8) {
            const iv4* p = (const iv4*)(csr + j);
            iv4 ia = p[0], ib = p[1];
            unsigned w[8];
            w[0] = sxu[(ia.x << 2) + f]; w[1] = sxu[(ia.y << 2) + f];
            w[2] = sxu[(ia.z << 2) + f]; w[3] = sxu[(ia.w << 2) + f];
            w[4] = sxu[(ib.x << 2) + f]; w[5] = sxu[(ib.y << 2) + f];
            w[6] = sxu[(ib.z << 2) + f]; w[7] = sxu[(ib.w << 2) + f];
            h2 s01 = uph(w[0]) + uph(w[1]);
            h2 s23 = uph(w[2]) + uph(w[3]);
            h2 s45 = uph(w[4]) + uph(w[5]);
            h2 s67 = uph(w[6]) + uph(w[7]);
            acc += (s01 + s23) + (s45 + s67);
        }
        sagg[loc][2*f]   = (float)acc.x;
        sagg[loc][2*f+1] = (float)acc.y;
        if (f == 0) sdis[loc] = dis[n];
    }
    __syncthreads();
    float dn = sdis[loc];
    // stage 2: h1 = lrelu(dis*(agg@W1)+b1); each lane does 16 features
#pragma unroll
    for (int q = 0; q < 16; ++q) {
        int k = (f << 4) + q;
        float s = 0.0f;
#pragma unroll
        for (int j = 0; j < IN_F; ++j) s += sagg[loc][j] * sW1[j * H1 + k];
        sh1[loc][k] = lrelu(s * dn + sb1[k]);
    }
    __syncthreads();
    // stage 3: t2 = dis*(h1@W2); each lane does 8 features, one 16B store
    float r[8];
#pragma unroll
    for (int q = 0; q < 8; ++q) {
        int f2 = (f << 3) + q;
        float s = 0.0f;
#pragma unroll
        for (int k = 0; k < H1; ++k) s += sh1[loc][k] * sW2[k * H2 + f2];
        r[q] = s * dn;
    }
    if (ok) {
        union { uint4 u; f16 h[8]; } pk;
#pragma unroll
        for (int q = 0; q < 8; ++q) pk.h[q] = (f16)r[q];
        *((uint4*)(t2 + n * H2 + f * 8)) = pk.u;
    }
}

// ---- layer-2 gather: 16 lanes/node, dword-packed t2 reads, fp16x2 accum ----
__global__ void k_gather2(const unsigned* __restrict__ t2u, const int* __restrict__ obeg,
                          const int* __restrict__ oend, const int* __restrict__ csr,
                          const float* __restrict__ dis, const float* __restrict__ b2,
                          const int* __restrict__ batch,
                          float* __restrict__ gsum, float* __restrict__ gcnt) {
    __shared__ float sv[16][H2];
    __shared__ int sg[16];
    int idx = blockIdx.x * blockDim.x + threadIdx.x;
    int n = idx >> 4;          // 16 nodes per 256-thread block
    int f = idx & 15;          // feature pair {2f, 2f+1}
    h2 acc = uph(t2u[(n << 4) + f]);
    int b = obeg[n], e = oend[n];
    int j = b;
    for (; j + 16 <= e; j += 16) {
        const iv4* p = (const iv4*)(csr + j);
        iv4 ia = p[0], ib = p[1], ic = p[2], id = p[3];
        unsigned w[16];
        w[0]  = t2u[(ia.x << 4) + f]; w[1]  = t2u[(ia.y << 4) + f];
        w[2]  = t2u[(ia.z << 4) + f]; w[3]  = t2u[(ia.w << 4) + f];
        w[4]  = t2u[(ib.x << 4) + f]; w[5]  = t2u[(ib.y << 4) + f];
        w[6]  = t2u[(ib.z << 4) + f]; w[7]  = t2u[(ib.w << 4) + f];
        w[8]  = t2u[(ic.x << 4) + f]; w[9]  = t2u[(ic.y << 4) + f];
        w[10] = t2u[(ic.z << 4) + f]; w[11] = t2u[(ic.w << 4) + f];
        w[12] = t2u[(id.x << 4) + f]; w[13] = t2u[(id.y << 4) + f];
        w[14] = t2u[(id.z << 4) + f]; w[15] = t2u[(id.w << 4) + f];
        h2 s0 = (uph(w[0])  + uph(w[1]))  + (uph(w[2])  + uph(w[3]));
        h2 s1 = (uph(w[4])  + uph(w[5]))  + (uph(w[6])  + uph(w[7]));
        h2 s2 = (uph(w[8])  + uph(w[9]))  + (uph(w[10]) + uph(w[11]));
        h2 s3 = (uph(w[12]) + uph(w[13])) + (uph(w[14]) + uph(w[15]));
        acc += (s0 + s1) + (s2 + s3);
    }
    if (j < e) {   // one remaining 8-chunk (lists are 8-aligned)
        const iv4* p = (const iv4*)(csr + j);
        iv4 ia = p[0], ib = p[1];
        unsigned w[8];
        w[0] = t2u[(ia.x << 4) + f]; w[1] = t2u[(ia.y << 4) + f];
        w[2] = t2u[(ia.z << 4) + f]; w[3] = t2u[(ia.w << 4) + f];
        w[4] = t2u[(ib.x << 4) + f]; w[5] = t2u[(ib.y << 4) + f];
        w[6] = t2u[(ib.z << 4) + f]; w[7] = t2u[(ib.w << 4) + f];
        h2 s0 = (uph(w[0]) + uph(w[1])) + (uph(w[2]) + uph(w[3]));
        h2 s1 = (uph(w[4]) + uph(w[5])) + (uph(w[6]) + uph(w[7]));
        acc += s0 + s1;
    }
    float dn = dis[n];
    float v0 = lrelu((float)acc.x * dn + b2[2*f]);
    float v1 = lrelu((float)acc.y * dn + b2[2*f+1]);
    int g = batch[n];
    int loc = threadIdx.x >> 4;
    sv[loc][2*f]   = v0;
    sv[loc][2*f+1] = v1;
    if (f == 0) sg[loc] = g;
    __syncthreads();
    bool leader = true;
    for (int l = 0; l < loc; ++l) leader &= (sg[l] != g);
    if (leader) {
        float s0 = v0, s1 = v1;
        float c = 1.0f;
        for (int l = loc + 1; l < 16; ++l)
            if (sg[l] == g) { s0 += sv[l][2*f]; s1 += sv[l][2*f+1]; c += 1.0f; }
        atomicAdd(&gsum[g * H2 + 2*f], s0);
        atomicAdd(&gsum[g * H2 + 2*f+1], s1);
        if (f == 0) atomicAdd(&gcnt[g], c);
    }
}

__global__ void k_final(const float* __restrict__ gsum, const float* __restrict__ gcnt,
                        const float* __restrict__ Wlin, const float* __restrict__ blin,
                        float* __restrict__ out) {
    int idx = blockIdx.x * blockDim.x + threadIdx.x;
    if (idx >= N_GRAPHS * 2) return;
    int g = idx >> 1;
    int t = idx & 1;
    float inv = 1.0f / fmaxf(gcnt[g], 1.0f);
    float s = blin[t];
#pragma unroll
    for (int ff = 0; ff < H2; ++ff)
        s += gsum[g * H2 + ff] * inv * Wlin[ff * 2 + t];
    out[idx] = s;
}

static inline int cdiv(long long a, int b) { return (int)((a + b - 1) / b); }

extern "C" void kernel_launch(void* const* d_in, const int* in_sizes, int n_in,
                              void* d_out, int out_size, void* d_ws, size_t ws_size,
                              hipStream_t stream) {
    const float* x    = (const float*)d_in[0];
    const int*   ei   = (const int*)d_in[1];
    const int*   batch= (const int*)d_in[2];
    const float* W1   = (const float*)d_in[3];
    const float* b1   = (const float*)d_in[4];
    const float* W2   = (const float*)d_in[5];
    const float* b2   = (const float*)d_in[6];
    const float* Wlin = (const float*)d_in[7];
    const float* blin = (const float*)d_in[8];
    float* out = (float*)d_out;

    const int* src = ei;
    const int* dst = ei + N_EDGES;

    // ---- workspace layout ----
    f16*   t2   = (f16*)d_ws;                           // 32*(N+1) fp16
    f16*   sx   = t2 + 32LL * (N_NODES + 1);            // 8*(N+1) fp16
    float* dis  = (float*)(sx + 8LL * (N_NODES + 1));   // N f32
    float* gsum = dis + N_NODES;                        // 32G
    float* gcnt = gsum + (long long)N_GRAPHS * H2;      // G
    size_t ioff = ((size_t)(gcnt + N_GRAPHS) + 15) & ~(size_t)15;
    int*  bcur2   = (int*)ioff;                         // NBIN (+pad)
    int*  obeg    = bcur2 + NBIN + 16;                  // N
    int*  oend    = obeg + N_NODES;                     // N
    unsigned* benc2 = (unsigned*)(oend + N_NODES);      // NBIN*CAP2
    int*  csr      = (int*)(benc2 + (long long)NBIN * CAP2);  // NBIN*CAP2R

    const int B = 256;

    k_init<<<cdiv(N_GRAPHS * H2 + N_GRAPHS, B), B, 0, stream>>>(
        gsum, bcur2, t2 + 32LL * N_NODES, sx + 8LL * N_NODES);

    k_bin400<<<NSEGB, B, 0, stream>>>(src, dst, bcur2, benc2);
    k_sort<<<NBIN, B, 0, stream>>>(benc2, bcur2, x, csr, obeg, oend, dis, sx);

    k_l1<<<cdiv(N_NODES, 64), B, 0, stream>>>((const unsigned*)sx, obeg, oend, csr,
                                              W1, b1, W2, dis, t2);
    k_gather2<<<cdiv((long long)N_NODES * 16, B), B, 0, stream>>>(
        (const unsigned*)t2, obeg, oend, csr, dis, b2, batch, gsum, gcnt);
    k_final<<<cdiv(N_GRAPHS * 2, B), B, 0, stream>>>(gsum, gcnt, Wlin, blin, out);
}

// Round 21
// 128.943 us; speedup vs baseline: 1.1548x; 1.1548x over previous
//
#include <hip/hip_runtime.h>

// GCN forward, round 21: r19 build (SEG=8192 LDS-staged counting sort,
// bslot stream-out) + fp8-e4m3 t2 table: 3.2MB fits one XCD L2, halving
// k_gather2's fetch; HW cvt_pk_f32_fp8 decode, 8 lanes/node.
//
//   dis[n] = rsqrt(deg_in[n] + 1)
//   layer1: aggx[n] = sx[n] + sum_{s->n} sx[s],  sx = (x*dis) fp16 [8-padded]
//           h1[n]   = lrelu(dis[n]*(aggx[n] @ W1) + b1)   [64] (LDS only)
//   layer2: t2[n]   = dis[n]*(h1[n] @ W2)  fp8-e4m3        [32]
//           h2[n]   = lrelu(dis[n]*(t2[n] + sum t2[s]) + b2)
//   pool:   gsum[batch[n]] += h2[n];  out = (gsum/cnt) @ Wlin + blin

#define N_NODES 100000
#define N_EDGES 3200000
#define N_GRAPHS 1024
#define IN_F 6
#define H1 64
#define H2 32
#define SLOPE 0.01f

#define NBIN 400             // bins of 250 dst nodes
#define BIN_N 250
#define CAP2 8704            // per-bin edge capacity (8000 avg + ~8 sigma)
#define CAP2R 10752          // per-bin padded CSR window

#define SEG 8192             // edges per k_bin400 block (r19 value)
#define NSEGB ((N_EDGES + SEG - 1) / SEG)   // 391

typedef _Float16 f16;
typedef _Float16 h2 __attribute__((ext_vector_type(2)));
typedef float f2 __attribute__((ext_vector_type(2)));
typedef int  iv4 __attribute__((ext_vector_type(4)));

static __device__ __forceinline__ float lrelu(float v) {
    return v > 0.0f ? v : SLOPE * v;
}

static __device__ __forceinline__ h2 uph(unsigned w) {
    union { unsigned u; h2 h; } cv; cv.u = w;
    return cv.h;
}

// decode 4 fp8-e4m3 packed in a dword -> two float2
static __device__ __forceinline__ void upk8(unsigned w, f2& lo, f2& hi) {
    lo = __builtin_amdgcn_cvt_pk_f32_fp8((int)w, false);
    hi = __builtin_amdgcn_cvt_pk_f32_fp8((int)w, true);
}

// encode 4 floats -> dword of 4 fp8-e4m3
static __device__ __forceinline__ unsigned pk8(float a, float b, float c, float d) {
    int v = __builtin_amdgcn_cvt_pk_fp8_f32(a, b, 0, false);
    v = __builtin_amdgcn_cvt_pk_fp8_f32(c, d, v, true);
    return (unsigned)v;
}

// ---- init: zero gsum/gcnt, bin cursors, zero rows ----
__global__ void k_init(float* __restrict__ gz, int* __restrict__ bz,
                       unsigned* __restrict__ t2z, f16* __restrict__ sxz) {
    int i = blockIdx.x * blockDim.x + threadIdx.x;
    if (i < N_GRAPHS * H2 + N_GRAPHS) gz[i] = 0.0f;
    if (i < NBIN + 16) bz[i] = 0;
    if (i < 8) t2z[i] = 0u;            // fp8 zero row (32 B)
    if (i < 8) sxz[i] = (f16)0.0f;
}

// ---- single-pass 400-bin counting sort of the edge list (r19) ----
__global__ void k_bin400(const int* __restrict__ src, const int* __restrict__ dst,
                         int* __restrict__ bcur2, unsigned* __restrict__ benc2) {
    __shared__ int hist[NBIN];
    __shared__ int lscan[NBIN];
    __shared__ int lcur[NBIN];
    __shared__ int gbase[NBIN];
    __shared__ int scn[512];
    __shared__ unsigned codes[SEG];          // 32 KB
    __shared__ unsigned short bslot[SEG];    // 16 KB
    int tid = threadIdx.x;
    for (int i = tid; i < NBIN; i += 256) hist[i] = 0;
    __syncthreads();
    int e0 = blockIdx.x * SEG;
    int e1 = e0 + SEG; if (e1 > N_EDGES) e1 = N_EDGES;
    int cnt = e1 - e0;
    const iv4* d4 = (const iv4*)dst;
    const iv4* s4 = (const iv4*)src;
    int i40 = e0 >> 2, i41 = e1 >> 2;
    // phase 1: histogram
    for (int i4 = i40 + tid; i4 < i41; i4 += 256) {
        iv4 v = __builtin_nontemporal_load(d4 + i4);
        atomicAdd(&hist[v.x / BIN_N], 1);
        atomicAdd(&hist[v.y / BIN_N], 1);
        atomicAdd(&hist[v.z / BIN_N], 1);
        atomicAdd(&hist[v.w / BIN_N], 1);
    }
    __syncthreads();
    // phase 2: scan 400 (padded to 512), reserve global space
    scn[tid]       = (tid < NBIN) ? hist[tid] : 0;
    scn[tid + 256] = (tid + 256 < NBIN) ? hist[tid + 256] : 0;
    __syncthreads();
    for (int off = 1; off < 512; off <<= 1) {
        int v0 = (tid >= off) ? scn[tid - off] : 0;
        int v1 = (tid + 256 >= off) ? scn[tid + 256 - off] : 0;
        __syncthreads();
        scn[tid] += v0;
        scn[tid + 256] += v1;
        __syncthreads();
    }
    if (tid < NBIN) {
        int h = hist[tid];
        int ls = scn[tid] - h;          // exclusive
        lscan[tid] = ls;
        lcur[tid] = ls;
        gbase[tid] = h ? atomicAdd(&bcur2[tid], h) : 0;
        for (int j = ls; j < ls + h; ++j) bslot[j] = (unsigned short)tid;
    }
    if (tid + 256 < NBIN) {
        int t = tid + 256;
        int h = hist[t];
        int ls = scn[t] - h;
        lscan[t] = ls;
        lcur[t] = ls;
        gbase[t] = h ? atomicAdd(&bcur2[t], h) : 0;
        for (int j = ls; j < ls + h; ++j) bslot[j] = (unsigned short)t;
    }
    __syncthreads();
    // phase 3: scatter codes (src<<8 | dst_local) into LDS runs
    for (int i4 = i40 + tid; i4 < i41; i4 += 256) {
        iv4 dv = __builtin_nontemporal_load(d4 + i4);
        iv4 sv = __builtin_nontemporal_load(s4 + i4);
        int b, p;
        b = dv.x / BIN_N; p = atomicAdd(&lcur[b], 1);
        codes[p] = ((unsigned)sv.x << 8) | (unsigned)(dv.x - b * BIN_N);
        b = dv.y / BIN_N; p = atomicAdd(&lcur[b], 1);
        codes[p] = ((unsigned)sv.y << 8) | (unsigned)(dv.y - b * BIN_N);
        b = dv.z / BIN_N; p = atomicAdd(&lcur[b], 1);
        codes[p] = ((unsigned)sv.z << 8) | (unsigned)(dv.z - b * BIN_N);
        b = dv.w / BIN_N; p = atomicAdd(&lcur[b], 1);
        codes[p] = ((unsigned)sv.w << 8) | (unsigned)(dv.w - b * BIN_N);
    }
    __syncthreads();
    // phase 4: stream runs out (consecutive slots -> consecutive global)
    for (int slot = tid; slot < cnt; slot += 256) {
        int b = bslot[slot];
        int g = gbase[b] + (slot - lscan[b]);
        benc2[(long long)b * CAP2 + g] = codes[slot];
    }
}

// ---- per-bin LDS counting sort -> windowed CSR + deg/dis/sx ----
__global__ void k_sort(const unsigned* __restrict__ benc2, const int* __restrict__ bcur2,
                       const float* __restrict__ x,
                       int* __restrict__ csr, int* __restrict__ obeg, int* __restrict__ oend,
                       float* __restrict__ dis, f16* __restrict__ sx) {
    __shared__ int hist[256];
    __shared__ int scn[256];
    __shared__ int lcur[256];
    int bin = blockIdx.x;
    int tid = threadIdx.x;
    hist[tid] = 0;
    __syncthreads();
    int cnt = bcur2[bin];
    const unsigned* p = benc2 + (long long)bin * CAP2;
    for (int i = tid; i < cnt; i += 256)
        atomicAdd(&hist[p[i] & 0xFFu], 1);
    __syncthreads();
    int deg = hist[tid];
    int pad = (deg + 7) & ~7;
    scn[tid] = pad;
    __syncthreads();
    for (int off = 1; off < 256; off <<= 1) {
        int v = 0;
        if (tid >= off) v = scn[tid - off];
        __syncthreads();
        if (tid >= off) scn[tid] += v;
        __syncthreads();
    }
    int excl = scn[tid] - pad;               // exclusive scan of padded degs
    int gbase = bin * CAP2R;
    lcur[tid] = gbase + excl;
    if (tid < BIN_N) {
        int n = bin * BIN_N + tid;
        obeg[n] = gbase + excl;
        oend[n] = gbase + excl + pad;
        float dn = rsqrtf((float)(deg + 1));
        dis[n] = dn;
#pragma unroll
        for (int j = 0; j < IN_F; ++j)
            sx[n * 8 + j] = (f16)(x[n * IN_F + j] * dn);
        sx[n * 8 + 6] = (f16)0.0f;
        sx[n * 8 + 7] = (f16)0.0f;
    }
    __syncthreads();
    for (int i = tid; i < cnt; i += 256) {
        unsigned c = p[i];
        int pos = atomicAdd(&lcur[c & 0xFFu], 1);
        csr[pos] = (int)(c >> 8);
    }
    __syncthreads();
    if (tid < BIN_N) {
        int end = gbase + excl + pad;
        for (int j = lcur[tid]; j < end; ++j) csr[j] = N_NODES;   // zero-row pad
    }
}

// ---- fused layer 1: gather(sx dwords, fp16x2 accum) -> h1 (LDS) -> t2 fp8 ----
// 64 nodes/block, 4 lanes/node; each lane owns one dword (2 fp16 feats).
__global__ void k_l1(const unsigned* __restrict__ sxu, const int* __restrict__ obeg,
                     const int* __restrict__ oend, const int* __restrict__ csr,
                     const float* __restrict__ W1, const float* __restrict__ b1,
                     const float* __restrict__ W2, const float* __restrict__ dis,
                     unsigned* __restrict__ t2) {
    __shared__ float sW1[IN_F * H1];
    __shared__ float sb1[H1];
    __shared__ float sW2[H1 * H2];
    __shared__ float sagg[64][9];       // +pad
    __shared__ float sh1[64][H1 + 1];   // +pad
    __shared__ float sdis[64];
    int tid = threadIdx.x;
    for (int i = tid; i < IN_F * H1; i += 256) sW1[i] = W1[i];
    if (tid < H1) sb1[tid] = b1[tid];
    for (int i = tid; i < H1 * H2; i += 256) sW2[i] = W2[i];
    int loc = tid >> 2;        // 0..63
    int f = tid & 3;           // dword index within 16B sx row
    int n = blockIdx.x * 64 + loc;
    bool ok = n < N_NODES;
    if (ok) {
        h2 acc = uph(sxu[(n << 2) + f]);
        int b = obeg[n], e = oend[n];
        for (int j = b; j < e; j += 8) {
            const iv4* p = (const iv4*)(csr + j);
            iv4 ia = p[0], ib = p[1];
            unsigned w[8];
            w[0] = sxu[(ia.x << 2) + f]; w[1] = sxu[(ia.y << 2) + f];
            w[2] = sxu[(ia.z << 2) + f]; w[3] = sxu[(ia.w << 2) + f];
            w[4] = sxu[(ib.x << 2) + f]; w[5] = sxu[(ib.y << 2) + f];
            w[6] = sxu[(ib.z << 2) + f]; w[7] = sxu[(ib.w << 2) + f];
            h2 s01 = uph(w[0]) + uph(w[1]);
            h2 s23 = uph(w[2]) + uph(w[3]);
            h2 s45 = uph(w[4]) + uph(w[5]);
            h2 s67 = uph(w[6]) + uph(w[7]);
            acc += (s01 + s23) + (s45 + s67);
        }
        sagg[loc][2*f]   = (float)acc.x;
        sagg[loc][2*f+1] = (float)acc.y;
        if (f == 0) sdis[loc] = dis[n];
    }
    __syncthreads();
    float dn = sdis[loc];
    // stage 2: h1 = lrelu(dis*(agg@W1)+b1); each lane does 16 features
#pragma unroll
    for (int q = 0; q < 16; ++q) {
        int k = (f << 4) + q;
        float s = 0.0f;
#pragma unroll
        for (int j = 0; j < IN_F; ++j) s += sagg[loc][j] * sW1[j * H1 + k];
        sh1[loc][k] = lrelu(s * dn + sb1[k]);
    }
    __syncthreads();
    // stage 3: t2 = dis*(h1@W2); each lane does 8 features -> 2 fp8 dwords
    float r[8];
#pragma unroll
    for (int q = 0; q < 8; ++q) {
        int f2i = (f << 3) + q;
        float s = 0.0f;
#pragma unroll
        for (int k = 0; k < H1; ++k) s += sh1[loc][k] * sW2[k * H2 + f2i];
        r[q] = s * dn;
    }
    if (ok) {
        uint2 pk;
        pk.x = pk8(r[0], r[1], r[2], r[3]);
        pk.y = pk8(r[4], r[5], r[6], r[7]);
        *((uint2*)(t2 + n * 8 + f * 2)) = pk;
    }
}

// ---- layer-2 gather: 8 lanes/node, fp8 dword rows (4 feats/lane) ----
__global__ void k_gather2(const unsigned* __restrict__ t2u, const int* __restrict__ obeg,
                          const int* __restrict__ oend, const int* __restrict__ csr,
                          const float* __restrict__ dis, const float* __restrict__ b2,
                          const int* __restrict__ batch,
                          float* __restrict__ gsum, float* __restrict__ gcnt) {
    __shared__ float sv[32][H2];
    __shared__ int sg[32];
    int idx = blockIdx.x * blockDim.x + threadIdx.x;
    int n = idx >> 3;          // 32 nodes per 256-thread block
    int f = idx & 7;           // dword = features 4f..4f+3
    f2 a01, a23;
    upk8(t2u[(n << 3) + f], a01, a23);
    int b = obeg[n], e = oend[n];
    int j = b;
    for (; j + 16 <= e; j += 16) {
        const iv4* p = (const iv4*)(csr + j);
        iv4 ia = p[0], ib = p[1], ic = p[2], id = p[3];
        unsigned w[16];
        w[0]  = t2u[(ia.x << 3) + f]; w[1]  = t2u[(ia.y << 3) + f];
        w[2]  = t2u[(ia.z << 3) + f]; w[3]  = t2u[(ia.w << 3) + f];
        w[4]  = t2u[(ib.x << 3) + f]; w[5]  = t2u[(ib.y << 3) + f];
        w[6]  = t2u[(ib.z << 3) + f]; w[7]  = t2u[(ib.w << 3) + f];
        w[8]  = t2u[(ic.x << 3) + f]; w[9]  = t2u[(ic.y << 3) + f];
        w[10] = t2u[(ic.z << 3) + f]; w[11] = t2u[(ic.w << 3) + f];
        w[12] = t2u[(id.x << 3) + f]; w[13] = t2u[(id.y << 3) + f];
        w[14] = t2u[(id.z << 3) + f]; w[15] = t2u[(id.w << 3) + f];
#pragma unroll
        for (int q = 0; q < 16; ++q) {
            f2 lo, hi;
            upk8(w[q], lo, hi);
            a01 += lo;
            a23 += hi;
        }
    }
    if (j < e) {   // one remaining 8-chunk (lists are 8-aligned)
        const iv4* p = (const iv4*)(csr + j);
        iv4 ia = p[0], ib = p[1];
        unsigned w[8];
        w[0] = t2u[(ia.x << 3) + f]; w[1] = t2u[(ia.y << 3) + f];
        w[2] = t2u[(ia.z << 3) + f]; w[3] = t2u[(ia.w << 3) + f];
        w[4] = t2u[(ib.x << 3) + f]; w[5] = t2u[(ib.y << 3) + f];
        w[6] = t2u[(ib.z << 3) + f]; w[7] = t2u[(ib.w << 3) + f];
#pragma unroll
        for (int q = 0; q < 8; ++q) {
            f2 lo, hi;
            upk8(w[q], lo, hi);
            a01 += lo;
            a23 += hi;
        }
    }
    float dn = dis[n];
    float v0 = lrelu(a01.x * dn + b2[4*f]);
    float v1 = lrelu(a01.y * dn + b2[4*f+1]);
    float v2 = lrelu(a23.x * dn + b2[4*f+2]);
    float v3 = lrelu(a23.y * dn + b2[4*f+3]);
    int g = batch[n];
    int loc = threadIdx.x >> 3;
    sv[loc][4*f]   = v0;
    sv[loc][4*f+1] = v1;
    sv[loc][4*f+2] = v2;
    sv[loc][4*f+3] = v3;
    if (f == 0) sg[loc] = g;
    __syncthreads();
    bool leader = true;
    for (int l = 0; l < loc; ++l) leader &= (sg[l] != g);
    if (leader) {
        float s0 = v0, s1 = v1, s2 = v2, s3 = v3;
        float c = 1.0f;
        for (int l = loc + 1; l < 32; ++l)
            if (sg[l] == g) {
                s0 += sv[l][4*f];   s1 += sv[l][4*f+1];
                s2 += sv[l][4*f+2]; s3 += sv[l][4*f+3];
                c += 1.0f;
            }
        atomicAdd(&gsum[g * H2 + 4*f],     s0);
        atomicAdd(&gsum[g * H2 + 4*f + 1], s1);
        atomicAdd(&gsum[g * H2 + 4*f + 2], s2);
        atomicAdd(&gsum[g * H2 + 4*f + 3], s3);
        if (f == 0) atomicAdd(&gcnt[g], c);
    }
}

__global__ void k_final(const float* __restrict__ gsum, const float* __restrict__ gcnt,
                        const float* __restrict__ Wlin, const float* __restrict__ blin,
                        float* __restrict__ out) {
    int idx = blockIdx.x * blockDim.x + threadIdx.x;
    if (idx >= N_GRAPHS * 2) return;
    int g = idx >> 1;
    int t = idx & 1;
    float inv = 1.0f / fmaxf(gcnt[g], 1.0f);
    float s = blin[t];
#pragma unroll
    for (int ff = 0; ff < H2; ++ff)
        s += gsum[g * H2 + ff] * inv * Wlin[ff * 2 + t];
    out[idx] = s;
}

static inline int cdiv(long long a, int b) { return (int)((a + b - 1) / b); }

extern "C" void kernel_launch(void* const* d_in, const int* in_sizes, int n_in,
                              void* d_out, int out_size, void* d_ws, size_t ws_size,
                              hipStream_t stream) {
    const float* x    = (const float*)d_in[0];
    const int*   ei   = (const int*)d_in[1];
    const int*   batch= (const int*)d_in[2];
    const float* W1   = (const float*)d_in[3];
    const float* b1   = (const float*)d_in[4];
    const float* W2   = (const float*)d_in[5];
    const float* b2   = (const float*)d_in[6];
    const float* Wlin = (const float*)d_in[7];
    const float* blin = (const float*)d_in[8];
    float* out = (float*)d_out;

    const int* src = ei;
    const int* dst = ei + N_EDGES;

    // ---- workspace layout ----
    unsigned* t2 = (unsigned*)d_ws;                     // 8*(N+1) dwords (fp8 rows)
    f16*   sx   = (f16*)(t2 + 8LL * (N_NODES + 1));     // 8*(N+1) fp16
    float* dis  = (float*)(sx + 8LL * (N_NODES + 1));   // N f32
    float* gsum = dis + N_NODES;                        // 32G
    float* gcnt = gsum + (long long)N_GRAPHS * H2;      // G
    size_t ioff = ((size_t)(gcnt + N_GRAPHS) + 15) & ~(size_t)15;
    int*  bcur2   = (int*)ioff;                         // NBIN (+pad)
    int*  obeg    = bcur2 + NBIN + 16;                  // N
    int*  oend    = obeg + N_NODES;                     // N
    unsigned* benc2 = (unsigned*)(oend + N_NODES);      // NBIN*CAP2
    int*  csr      = (int*)(benc2 + (long long)NBIN * CAP2);  // NBIN*CAP2R

    const int B = 256;

    k_init<<<cdiv(N_GRAPHS * H2 + N_GRAPHS, B), B, 0, stream>>>(
        gsum, bcur2, t2 + 8LL * N_NODES, sx + 8LL * N_NODES);

    k_bin400<<<NSEGB, B, 0, stream>>>(src, dst, bcur2, benc2);
    k_sort<<<NBIN, B, 0, stream>>>(benc2, bcur2, x, csr, obeg, oend, dis, sx);

    k_l1<<<cdiv(N_NODES, 64), B, 0, stream>>>((const unsigned*)sx, obeg, oend, csr,
                                              W1, b1, W2, dis, t2);
    k_gather2<<<cdiv((long long)N_NODES * 8, B), B, 0, stream>>>(
        (const unsigned*)t2, obeg, oend, csr, dis, b2, batch, gsum, gcnt);
    k_final<<<cdiv(N_GRAPHS * 2, B), B, 0, stream>>>(gsum, gcnt, Wlin, blin, out);
}

// Round 22
// 118.237 us; speedup vs baseline: 1.2594x; 1.0905x over previous
//
#include <hip/hip_runtime.h>

// GCN forward, round 22: r21 (fp8 t2 table) + XCD-private benc2 regions in
// the binning pass. Each workgroup reads its physical XCD id (s_getreg
// HW_REG_XCC_ID) and streams its bin runs into that XCD's region, so
// run-boundary cache lines are only shared by same-XCD blocks -> they merge
// in the local L2 instead of cross-XCD partial-line RMW at the fabric.
//
//   dis[n] = rsqrt(deg_in[n] + 1)
//   layer1: aggx[n] = sx[n] + sum_{s->n} sx[s],  sx = (x*dis) fp16 [8-padded]
//           h1[n]   = lrelu(dis[n]*(aggx[n] @ W1) + b1)   [64] (LDS only)
//   layer2: t2[n]   = dis[n]*(h1[n] @ W2)  fp8-e4m3        [32]
//           h2[n]   = lrelu(dis[n]*(t2[n] + sum t2[s]) + b2)
//   pool:   gsum[batch[n]] += h2[n];  out = (gsum/cnt) @ Wlin + blin

#define N_NODES 100000
#define N_EDGES 3200000
#define N_GRAPHS 1024
#define IN_F 6
#define H1 64
#define H2 32
#define SLOPE 0.01f

#define NBIN 400             // bins of 250 dst nodes
#define BIN_N 250
#define NXCD 8
#define CAP2X 3072           // per-(xcd,bin) capacity (avg ~1000, huge margin)
#define CAP2R 10752          // per-bin padded CSR window

#define SEG 8192             // edges per k_bin400 block
#define NSEGB ((N_EDGES + SEG - 1) / SEG)   // 391

// hwreg(HW_REG_XCC_ID=20, offset=0, size=8) -> ((8-1)<<11)|(0<<6)|20
#define XCC_ID_REG 14356

typedef _Float16 f16;
typedef _Float16 h2 __attribute__((ext_vector_type(2)));
typedef float f2 __attribute__((ext_vector_type(2)));
typedef int  iv4 __attribute__((ext_vector_type(4)));

static __device__ __forceinline__ float lrelu(float v) {
    return v > 0.0f ? v : SLOPE * v;
}

static __device__ __forceinline__ h2 uph(unsigned w) {
    union { unsigned u; h2 h; } cv; cv.u = w;
    return cv.h;
}

// decode 4 fp8-e4m3 packed in a dword -> two float2
static __device__ __forceinline__ void upk8(unsigned w, f2& lo, f2& hi) {
    lo = __builtin_amdgcn_cvt_pk_f32_fp8((int)w, false);
    hi = __builtin_amdgcn_cvt_pk_f32_fp8((int)w, true);
}

// encode 4 floats -> dword of 4 fp8-e4m3
static __device__ __forceinline__ unsigned pk8(float a, float b, float c, float d) {
    int v = __builtin_amdgcn_cvt_pk_fp8_f32(a, b, 0, false);
    v = __builtin_amdgcn_cvt_pk_fp8_f32(c, d, v, true);
    return (unsigned)v;
}

// ---- init: zero gsum/gcnt, bin cursors, zero rows ----
__global__ void k_init(float* __restrict__ gz, int* __restrict__ bz,
                       unsigned* __restrict__ t2z, f16* __restrict__ sxz) {
    int i = blockIdx.x * blockDim.x + threadIdx.x;
    if (i < N_GRAPHS * H2 + N_GRAPHS) gz[i] = 0.0f;
    if (i < NXCD * NBIN + 16) bz[i] = 0;
    if (i < 8) t2z[i] = 0u;            // fp8 zero row (32 B)
    if (i < 8) sxz[i] = (f16)0.0f;
}

// ---- single-pass 400-bin counting sort; XCD-private output regions ----
__global__ void k_bin400(const int* __restrict__ src, const int* __restrict__ dst,
                         int* __restrict__ bcur2, unsigned* __restrict__ benc2) {
    __shared__ int hist[NBIN];
    __shared__ int lscan[NBIN];
    __shared__ int lcur[NBIN];
    __shared__ int gbase[NBIN];
    __shared__ int scn[512];
    __shared__ unsigned codes[SEG];          // 32 KB
    __shared__ unsigned short bslot[SEG];    // 16 KB
    int tid = threadIdx.x;
    int xcd = __builtin_amdgcn_s_getreg(XCC_ID_REG) & (NXCD - 1);
    int* mycur = bcur2 + xcd * NBIN;
    unsigned* myenc = benc2 + (long long)xcd * NBIN * CAP2X;
    for (int i = tid; i < NBIN; i += 256) hist[i] = 0;
    __syncthreads();
    int e0 = blockIdx.x * SEG;
    int e1 = e0 + SEG; if (e1 > N_EDGES) e1 = N_EDGES;
    int cnt = e1 - e0;
    const iv4* d4 = (const iv4*)dst;
    const iv4* s4 = (const iv4*)src;
    int i40 = e0 >> 2, i41 = e1 >> 2;
    // phase 1: histogram
    for (int i4 = i40 + tid; i4 < i41; i4 += 256) {
        iv4 v = __builtin_nontemporal_load(d4 + i4);
        atomicAdd(&hist[v.x / BIN_N], 1);
        atomicAdd(&hist[v.y / BIN_N], 1);
        atomicAdd(&hist[v.z / BIN_N], 1);
        atomicAdd(&hist[v.w / BIN_N], 1);
    }
    __syncthreads();
    // phase 2: scan 400 (padded to 512), reserve space in the XCD region
    scn[tid]       = (tid < NBIN) ? hist[tid] : 0;
    scn[tid + 256] = (tid + 256 < NBIN) ? hist[tid + 256] : 0;
    __syncthreads();
    for (int off = 1; off < 512; off <<= 1) {
        int v0 = (tid >= off) ? scn[tid - off] : 0;
        int v1 = (tid + 256 >= off) ? scn[tid + 256 - off] : 0;
        __syncthreads();
        scn[tid] += v0;
        scn[tid + 256] += v1;
        __syncthreads();
    }
    if (tid < NBIN) {
        int h = hist[tid];
        int ls = scn[tid] - h;          // exclusive
        lscan[tid] = ls;
        lcur[tid] = ls;
        gbase[tid] = h ? atomicAdd(&mycur[tid], h) : 0;
        for (int j = ls; j < ls + h; ++j) bslot[j] = (unsigned short)tid;
    }
    if (tid + 256 < NBIN) {
        int t = tid + 256;
        int h = hist[t];
        int ls = scn[t] - h;
        lscan[t] = ls;
        lcur[t] = ls;
        gbase[t] = h ? atomicAdd(&mycur[t], h) : 0;
        for (int j = ls; j < ls + h; ++j) bslot[j] = (unsigned short)t;
    }
    __syncthreads();
    // phase 3: scatter codes (src<<8 | dst_local) into LDS runs
    for (int i4 = i40 + tid; i4 < i41; i4 += 256) {
        iv4 dv = __builtin_nontemporal_load(d4 + i4);
        iv4 sv = __builtin_nontemporal_load(s4 + i4);
        int b, p;
        b = dv.x / BIN_N; p = atomicAdd(&lcur[b], 1);
        codes[p] = ((unsigned)sv.x << 8) | (unsigned)(dv.x - b * BIN_N);
        b = dv.y / BIN_N; p = atomicAdd(&lcur[b], 1);
        codes[p] = ((unsigned)sv.y << 8) | (unsigned)(dv.y - b * BIN_N);
        b = dv.z / BIN_N; p = atomicAdd(&lcur[b], 1);
        codes[p] = ((unsigned)sv.z << 8) | (unsigned)(dv.z - b * BIN_N);
        b = dv.w / BIN_N; p = atomicAdd(&lcur[b], 1);
        codes[p] = ((unsigned)sv.w << 8) | (unsigned)(dv.w - b * BIN_N);
    }
    __syncthreads();
    // phase 4: stream runs out (consecutive slots -> consecutive global,
    // into this XCD's private region)
    for (int slot = tid; slot < cnt; slot += 256) {
        int b = bslot[slot];
        int g = gbase[b] + (slot - lscan[b]);
        myenc[(long long)b * CAP2X + g] = codes[slot];
    }
}

// ---- per-bin LDS counting sort over the 8 XCD regions -> windowed CSR ----
__global__ void k_sort(const unsigned* __restrict__ benc2, const int* __restrict__ bcur2,
                       const float* __restrict__ x,
                       int* __restrict__ csr, int* __restrict__ obeg, int* __restrict__ oend,
                       float* __restrict__ dis, f16* __restrict__ sx) {
    __shared__ int hist[256];
    __shared__ int scn[256];
    __shared__ int lcur[256];
    int bin = blockIdx.x;
    int tid = threadIdx.x;
    hist[tid] = 0;
    __syncthreads();
    for (int xc = 0; xc < NXCD; ++xc) {
        int cnt = bcur2[xc * NBIN + bin];
        const unsigned* p = benc2 + ((long long)xc * NBIN + bin) * CAP2X;
        for (int i = tid; i < cnt; i += 256)
            atomicAdd(&hist[p[i] & 0xFFu], 1);
    }
    __syncthreads();
    int deg = hist[tid];
    int pad = (deg + 7) & ~7;
    scn[tid] = pad;
    __syncthreads();
    for (int off = 1; off < 256; off <<= 1) {
        int v = 0;
        if (tid >= off) v = scn[tid - off];
        __syncthreads();
        if (tid >= off) scn[tid] += v;
        __syncthreads();
    }
    int excl = scn[tid] - pad;               // exclusive scan of padded degs
    int gbase = bin * CAP2R;
    lcur[tid] = gbase + excl;
    if (tid < BIN_N) {
        int n = bin * BIN_N + tid;
        obeg[n] = gbase + excl;
        oend[n] = gbase + excl + pad;
        float dn = rsqrtf((float)(deg + 1));
        dis[n] = dn;
#pragma unroll
        for (int j = 0; j < IN_F; ++j)
            sx[n * 8 + j] = (f16)(x[n * IN_F + j] * dn);
        sx[n * 8 + 6] = (f16)0.0f;
        sx[n * 8 + 7] = (f16)0.0f;
    }
    __syncthreads();
    for (int xc = 0; xc < NXCD; ++xc) {
        int cnt = bcur2[xc * NBIN + bin];
        const unsigned* p = benc2 + ((long long)xc * NBIN + bin) * CAP2X;
        for (int i = tid; i < cnt; i += 256) {
            unsigned c = p[i];
            int pos = atomicAdd(&lcur[c & 0xFFu], 1);
            csr[pos] = (int)(c >> 8);
        }
    }
    __syncthreads();
    if (tid < BIN_N) {
        int end = gbase + excl + pad;
        for (int j = lcur[tid]; j < end; ++j) csr[j] = N_NODES;   // zero-row pad
    }
}

// ---- fused layer 1: gather(sx dwords, fp16x2 accum) -> h1 (LDS) -> t2 fp8 ----
// 64 nodes/block, 4 lanes/node; each lane owns one dword (2 fp16 feats).
__global__ void k_l1(const unsigned* __restrict__ sxu, const int* __restrict__ obeg,
                     const int* __restrict__ oend, const int* __restrict__ csr,
                     const float* __restrict__ W1, const float* __restrict__ b1,
                     const float* __restrict__ W2, const float* __restrict__ dis,
                     unsigned* __restrict__ t2) {
    __shared__ float sW1[IN_F * H1];
    __shared__ float sb1[H1];
    __shared__ float sW2[H1 * H2];
    __shared__ float sagg[64][9];       // +pad
    __shared__ float sh1[64][H1 + 1];   // +pad
    __shared__ float sdis[64];
    int tid = threadIdx.x;
    for (int i = tid; i < IN_F * H1; i += 256) sW1[i] = W1[i];
    if (tid < H1) sb1[tid] = b1[tid];
    for (int i = tid; i < H1 * H2; i += 256) sW2[i] = W2[i];
    int loc = tid >> 2;        // 0..63
    int f = tid & 3;           // dword index within 16B sx row
    int n = blockIdx.x * 64 + loc;
    bool ok = n < N_NODES;
    if (ok) {
        h2 acc = uph(sxu[(n << 2) + f]);
        int b = obeg[n], e = oend[n];
        for (int j = b; j < e; j += 8) {
            const iv4* p = (const iv4*)(csr + j);
            iv4 ia = p[0], ib = p[1];
            unsigned w[8];
            w[0] = sxu[(ia.x << 2) + f]; w[1] = sxu[(ia.y << 2) + f];
            w[2] = sxu[(ia.z << 2) + f]; w[3] = sxu[(ia.w << 2) + f];
            w[4] = sxu[(ib.x << 2) + f]; w[5] = sxu[(ib.y << 2) + f];
            w[6] = sxu[(ib.z << 2) + f]; w[7] = sxu[(ib.w << 2) + f];
            h2 s01 = uph(w[0]) + uph(w[1]);
            h2 s23 = uph(w[2]) + uph(w[3]);
            h2 s45 = uph(w[4]) + uph(w[5]);
            h2 s67 = uph(w[6]) + uph(w[7]);
            acc += (s01 + s23) + (s45 + s67);
        }
        sagg[loc][2*f]   = (float)acc.x;
        sagg[loc][2*f+1] = (float)acc.y;
        if (f == 0) sdis[loc] = dis[n];
    }
    __syncthreads();
    float dn = sdis[loc];
    // stage 2: h1 = lrelu(dis*(agg@W1)+b1); each lane does 16 features
#pragma unroll
    for (int q = 0; q < 16; ++q) {
        int k = (f << 4) + q;
        float s = 0.0f;
#pragma unroll
        for (int j = 0; j < IN_F; ++j) s += sagg[loc][j] * sW1[j * H1 + k];
        sh1[loc][k] = lrelu(s * dn + sb1[k]);
    }
    __syncthreads();
    // stage 3: t2 = dis*(h1@W2); each lane does 8 features -> 2 fp8 dwords
    float r[8];
#pragma unroll
    for (int q = 0; q < 8; ++q) {
        int f2i = (f << 3) + q;
        float s = 0.0f;
#pragma unroll
        for (int k = 0; k < H1; ++k) s += sh1[loc][k] * sW2[k * H2 + f2i];
        r[q] = s * dn;
    }
    if (ok) {
        uint2 pk;
        pk.x = pk8(r[0], r[1], r[2], r[3]);
        pk.y = pk8(r[4], r[5], r[6], r[7]);
        *((uint2*)(t2 + n * 8 + f * 2)) = pk;
    }
}

// ---- layer-2 gather: 8 lanes/node, fp8 dword rows (4 feats/lane) ----
__global__ void k_gather2(const unsigned* __restrict__ t2u, const int* __restrict__ obeg,
                          const int* __restrict__ oend, const int* __restrict__ csr,
                          const float* __restrict__ dis, const float* __restrict__ b2,
                          const int* __restrict__ batch,
                          float* __restrict__ gsum, float* __restrict__ gcnt) {
    __shared__ float sv[32][H2];
    __shared__ int sg[32];
    int idx = blockIdx.x * blockDim.x + threadIdx.x;
    int n = idx >> 3;          // 32 nodes per 256-thread block
    int f = idx & 7;           // dword = features 4f..4f+3
    f2 a01, a23;
    upk8(t2u[(n << 3) + f], a01, a23);
    int b = obeg[n], e = oend[n];
    int j = b;
    for (; j + 16 <= e; j += 16) {
        const iv4* p = (const iv4*)(csr + j);
        iv4 ia = p[0], ib = p[1], ic = p[2], id = p[3];
        unsigned w[16];
        w[0]  = t2u[(ia.x << 3) + f]; w[1]  = t2u[(ia.y << 3) + f];
        w[2]  = t2u[(ia.z << 3) + f]; w[3]  = t2u[(ia.w << 3) + f];
        w[4]  = t2u[(ib.x << 3) + f]; w[5]  = t2u[(ib.y << 3) + f];
        w[6]  = t2u[(ib.z << 3) + f]; w[7]  = t2u[(ib.w << 3) + f];
        w[8]  = t2u[(ic.x << 3) + f]; w[9]  = t2u[(ic.y << 3) + f];
        w[10] = t2u[(ic.z << 3) + f]; w[11] = t2u[(ic.w << 3) + f];
        w[12] = t2u[(id.x << 3) + f]; w[13] = t2u[(id.y << 3) + f];
        w[14] = t2u[(id.z << 3) + f]; w[15] = t2u[(id.w << 3) + f];
#pragma unroll
        for (int q = 0; q < 16; ++q) {
            f2 lo, hi;
            upk8(w[q], lo, hi);
            a01 += lo;
            a23 += hi;
        }
    }
    if (j < e) {   // one remaining 8-chunk (lists are 8-aligned)
        const iv4* p = (const iv4*)(csr + j);
        iv4 ia = p[0], ib = p[1];
        unsigned w[8];
        w[0] = t2u[(ia.x << 3) + f]; w[1] = t2u[(ia.y << 3) + f];
        w[2] = t2u[(ia.z << 3) + f]; w[3] = t2u[(ia.w << 3) + f];
        w[4] = t2u[(ib.x << 3) + f]; w[5] = t2u[(ib.y << 3) + f];
        w[6] = t2u[(ib.z << 3) + f]; w[7] = t2u[(ib.w << 3) + f];
#pragma unroll
        for (int q = 0; q < 8; ++q) {
            f2 lo, hi;
            upk8(w[q], lo, hi);
            a01 += lo;
            a23 += hi;
        }
    }
    float dn = dis[n];
    float v0 = lrelu(a01.x * dn + b2[4*f]);
    float v1 = lrelu(a01.y * dn + b2[4*f+1]);
    float v2 = lrelu(a23.x * dn + b2[4*f+2]);
    float v3 = lrelu(a23.y * dn + b2[4*f+3]);
    int g = batch[n];
    int loc = threadIdx.x >> 3;
    sv[loc][4*f]   = v0;
    sv[loc][4*f+1] = v1;
    sv[loc][4*f+2] = v2;
    sv[loc][4*f+3] = v3;
    if (f == 0) sg[loc] = g;
    __syncthreads();
    bool leader = true;
    for (int l = 0; l < loc; ++l) leader &= (sg[l] != g);
    if (leader) {
        float s0 = v0, s1 = v1, s2 = v2, s3 = v3;
        float c = 1.0f;
        for (int l = loc + 1; l < 32; ++l)
            if (sg[l] == g) {
                s0 += sv[l][4*f];   s1 += sv[l][4*f+1];
                s2 += sv[l][4*f+2]; s3 += sv[l][4*f+3];
                c += 1.0f;
            }
        atomicAdd(&gsum[g * H2 + 4*f],     s0);
        atomicAdd(&gsum[g * H2 + 4*f + 1], s1);
        atomicAdd(&gsum[g * H2 + 4*f + 2], s2);
        atomicAdd(&gsum[g * H2 + 4*f + 3], s3);
        if (f == 0) atomicAdd(&gcnt[g], c);
    }
}

__global__ void k_final(const float* __restrict__ gsum, const float* __restrict__ gcnt,
                        const float* __restrict__ Wlin, const float* __restrict__ blin,
                        float* __restrict__ out) {
    int idx = blockIdx.x * blockDim.x + threadIdx.x;
    if (idx >= N_GRAPHS * 2) return;
    int g = idx >> 1;
    int t = idx & 1;
    float inv = 1.0f / fmaxf(gcnt[g], 1.0f);
    float s = blin[t];
#pragma unroll
    for (int ff = 0; ff < H2; ++ff)
        s += gsum[g * H2 + ff] * inv * Wlin[ff * 2 + t];
    out[idx] = s;
}

static inline int cdiv(long long a, int b) { return (int)((a + b - 1) / b); }

extern "C" void kernel_launch(void* const* d_in, const int* in_sizes, int n_in,
                              void* d_out, int out_size, void* d_ws, size_t ws_size,
                              hipStream_t stream) {
    const float* x    = (const float*)d_in[0];
    const int*   ei   = (const int*)d_in[1];
    const int*   batch= (const int*)d_in[2];
    const float* W1   = (const float*)d_in[3];
    const float* b1   = (const float*)d_in[4];
    const float* W2   = (const float*)d_in[5];
    const float* b2   = (const float*)d_in[6];
    const float* Wlin = (const float*)d_in[7];
    const float* blin = (const float*)d_in[8];
    float* out = (float*)d_out;

    const int* src = ei;
    const int* dst = ei + N_EDGES;

    // ---- workspace layout ----
    unsigned* t2 = (unsigned*)d_ws;                     // 8*(N+1) dwords (fp8 rows)
    f16*   sx   = (f16*)(t2 + 8LL * (N_NODES + 1));     // 8*(N+1) fp16
    float* dis  = (float*)(sx + 8LL * (N_NODES + 1));   // N f32
    float* gsum = dis + N_NODES;                        // 32G
    float* gcnt = gsum + (long long)N_GRAPHS * H2;      // G
    size_t ioff = ((size_t)(gcnt + N_GRAPHS) + 63) & ~(size_t)63;
    int*  bcur2   = (int*)ioff;                         // NXCD*NBIN (+pad)
    int*  obeg    = bcur2 + NXCD * NBIN + 16;           // N
    int*  oend    = obeg + N_NODES;                     // N
    size_t boff = ((size_t)(oend + N_NODES) + 63) & ~(size_t)63;
    unsigned* benc2 = (unsigned*)boff;                  // NXCD*NBIN*CAP2X
    int*  csr      = (int*)(benc2 + (long long)NXCD * NBIN * CAP2X);  // NBIN*CAP2R

    const int B = 256;

    k_init<<<cdiv(N_GRAPHS * H2 + N_GRAPHS, B), B, 0, stream>>>(
        gsum, bcur2, t2 + 8LL * N_NODES, sx + 8LL * N_NODES);

    k_bin400<<<NSEGB, B, 0, stream>>>(src, dst, bcur2, benc2);
    k_sort<<<NBIN, B, 0, stream>>>(benc2, bcur2, x, csr, obeg, oend, dis, sx);

    k_l1<<<cdiv(N_NODES, 64), B, 0, stream>>>((const unsigned*)sx, obeg, oend, csr,
                                              W1, b1, W2, dis, t2);
    k_gather2<<<cdiv((long long)N_NODES * 8, B), B, 0, stream>>>(
        (const unsigned*)t2, obeg, oend, csr, dis, b2, batch, gsum, gcnt);
    k_final<<<cdiv(N_GRAPHS * 2, B), B, 0, stream>>>(gsum, gcnt, Wlin, blin, out);
}

// Round 23
// 112.069 us; speedup vs baseline: 1.3287x; 1.0550x over previous
//
#include <hip/hip_runtime.h>

// GCN forward, round 23: r22 (fp8 t2, XCD-private benc2 regions) +
// k_sort stages its bin's codes in LDS once (single benc2 pass instead of
// two) + k_l1 gather unrolled x16 for deeper MLP.
//
//   dis[n] = rsqrt(deg_in[n] + 1)
//   layer1: aggx[n] = sx[n] + sum_{s->n} sx[s],  sx = (x*dis) fp16 [8-padded]
//           h1[n]   = lrelu(dis[n]*(aggx[n] @ W1) + b1)   [64] (LDS only)
//   layer2: t2[n]   = dis[n]*(h1[n] @ W2)  fp8-e4m3        [32]
//           h2[n]   = lrelu(dis[n]*(t2[n] + sum t2[s]) + b2)
//   pool:   gsum[batch[n]] += h2[n];  out = (gsum/cnt) @ Wlin + blin

#define N_NODES 100000
#define N_EDGES 3200000
#define N_GRAPHS 1024
#define IN_F 6
#define H1 64
#define H2 32
#define SLOPE 0.01f

#define NBIN 400             // bins of 250 dst nodes
#define BIN_N 250
#define NXCD 8
#define CAP2X 3072           // per-(xcd,bin) capacity
#define CAP2 8704            // max codes per bin (8000 avg + 8 sigma)
#define CAP2R 10752          // per-bin padded CSR window

#define SEG 8192             // edges per k_bin400 block
#define NSEGB ((N_EDGES + SEG - 1) / SEG)   // 391

// hwreg(HW_REG_XCC_ID=20, offset=0, size=8) -> ((8-1)<<11)|(0<<6)|20
#define XCC_ID_REG 14356

typedef _Float16 f16;
typedef _Float16 h2 __attribute__((ext_vector_type(2)));
typedef float f2 __attribute__((ext_vector_type(2)));
typedef int  iv4 __attribute__((ext_vector_type(4)));

static __device__ __forceinline__ float lrelu(float v) {
    return v > 0.0f ? v : SLOPE * v;
}

static __device__ __forceinline__ h2 uph(unsigned w) {
    union { unsigned u; h2 h; } cv; cv.u = w;
    return cv.h;
}

// decode 4 fp8-e4m3 packed in a dword -> two float2
static __device__ __forceinline__ void upk8(unsigned w, f2& lo, f2& hi) {
    lo = __builtin_amdgcn_cvt_pk_f32_fp8((int)w, false);
    hi = __builtin_amdgcn_cvt_pk_f32_fp8((int)w, true);
}

// encode 4 floats -> dword of 4 fp8-e4m3
static __device__ __forceinline__ unsigned pk8(float a, float b, float c, float d) {
    int v = __builtin_amdgcn_cvt_pk_fp8_f32(a, b, 0, false);
    v = __builtin_amdgcn_cvt_pk_fp8_f32(c, d, v, true);
    return (unsigned)v;
}

// ---- init: zero gsum/gcnt, bin cursors, zero rows ----
__global__ void k_init(float* __restrict__ gz, int* __restrict__ bz,
                       unsigned* __restrict__ t2z, f16* __restrict__ sxz) {
    int i = blockIdx.x * blockDim.x + threadIdx.x;
    if (i < N_GRAPHS * H2 + N_GRAPHS) gz[i] = 0.0f;
    if (i < NXCD * NBIN + 16) bz[i] = 0;
    if (i < 8) t2z[i] = 0u;            // fp8 zero row (32 B)
    if (i < 8) sxz[i] = (f16)0.0f;
}

// ---- single-pass 400-bin counting sort; XCD-private output regions ----
__global__ void k_bin400(const int* __restrict__ src, const int* __restrict__ dst,
                         int* __restrict__ bcur2, unsigned* __restrict__ benc2) {
    __shared__ int hist[NBIN];
    __shared__ int lscan[NBIN];
    __shared__ int lcur[NBIN];
    __shared__ int gbase[NBIN];
    __shared__ int scn[512];
    __shared__ unsigned codes[SEG];          // 32 KB
    __shared__ unsigned short bslot[SEG];    // 16 KB
    int tid = threadIdx.x;
    int xcd = __builtin_amdgcn_s_getreg(XCC_ID_REG) & (NXCD - 1);
    int* mycur = bcur2 + xcd * NBIN;
    unsigned* myenc = benc2 + (long long)xcd * NBIN * CAP2X;
    for (int i = tid; i < NBIN; i += 256) hist[i] = 0;
    __syncthreads();
    int e0 = blockIdx.x * SEG;
    int e1 = e0 + SEG; if (e1 > N_EDGES) e1 = N_EDGES;
    int cnt = e1 - e0;
    const iv4* d4 = (const iv4*)dst;
    const iv4* s4 = (const iv4*)src;
    int i40 = e0 >> 2, i41 = e1 >> 2;
    // phase 1: histogram
    for (int i4 = i40 + tid; i4 < i41; i4 += 256) {
        iv4 v = __builtin_nontemporal_load(d4 + i4);
        atomicAdd(&hist[v.x / BIN_N], 1);
        atomicAdd(&hist[v.y / BIN_N], 1);
        atomicAdd(&hist[v.z / BIN_N], 1);
        atomicAdd(&hist[v.w / BIN_N], 1);
    }
    __syncthreads();
    // phase 2: scan 400 (padded to 512), reserve space in the XCD region
    scn[tid]       = (tid < NBIN) ? hist[tid] : 0;
    scn[tid + 256] = (tid + 256 < NBIN) ? hist[tid + 256] : 0;
    __syncthreads();
    for (int off = 1; off < 512; off <<= 1) {
        int v0 = (tid >= off) ? scn[tid - off] : 0;
        int v1 = (tid + 256 >= off) ? scn[tid + 256 - off] : 0;
        __syncthreads();
        scn[tid] += v0;
        scn[tid + 256] += v1;
        __syncthreads();
    }
    if (tid < NBIN) {
        int h = hist[tid];
        int ls = scn[tid] - h;          // exclusive
        lscan[tid] = ls;
        lcur[tid] = ls;
        gbase[tid] = h ? atomicAdd(&mycur[tid], h) : 0;
        for (int j = ls; j < ls + h; ++j) bslot[j] = (unsigned short)tid;
    }
    if (tid + 256 < NBIN) {
        int t = tid + 256;
        int h = hist[t];
        int ls = scn[t] - h;
        lscan[t] = ls;
        lcur[t] = ls;
        gbase[t] = h ? atomicAdd(&mycur[t], h) : 0;
        for (int j = ls; j < ls + h; ++j) bslot[j] = (unsigned short)t;
    }
    __syncthreads();
    // phase 3: scatter codes (src<<8 | dst_local) into LDS runs
    for (int i4 = i40 + tid; i4 < i41; i4 += 256) {
        iv4 dv = __builtin_nontemporal_load(d4 + i4);
        iv4 sv = __builtin_nontemporal_load(s4 + i4);
        int b, p;
        b = dv.x / BIN_N; p = atomicAdd(&lcur[b], 1);
        codes[p] = ((unsigned)sv.x << 8) | (unsigned)(dv.x - b * BIN_N);
        b = dv.y / BIN_N; p = atomicAdd(&lcur[b], 1);
        codes[p] = ((unsigned)sv.y << 8) | (unsigned)(dv.y - b * BIN_N);
        b = dv.z / BIN_N; p = atomicAdd(&lcur[b], 1);
        codes[p] = ((unsigned)sv.z << 8) | (unsigned)(dv.z - b * BIN_N);
        b = dv.w / BIN_N; p = atomicAdd(&lcur[b], 1);
        codes[p] = ((unsigned)sv.w << 8) | (unsigned)(dv.w - b * BIN_N);
    }
    __syncthreads();
    // phase 4: stream runs out (consecutive slots -> consecutive global,
    // into this XCD's private region)
    for (int slot = tid; slot < cnt; slot += 256) {
        int b = bslot[slot];
        int g = gbase[b] + (slot - lscan[b]);
        myenc[(long long)b * CAP2X + g] = codes[slot];
    }
}

// ---- per-bin counting sort: stage codes in LDS once, then hist+scatter ----
__global__ void k_sort(const unsigned* __restrict__ benc2, const int* __restrict__ bcur2,
                       const float* __restrict__ x,
                       int* __restrict__ csr, int* __restrict__ obeg, int* __restrict__ oend,
                       float* __restrict__ dis, f16* __restrict__ sx) {
    __shared__ unsigned codes[CAP2];     // 34.8 KB
    __shared__ int hist[256];
    __shared__ int scn[256];
    __shared__ int lcur[256];
    int bin = blockIdx.x;
    int tid = threadIdx.x;
    hist[tid] = 0;
    __syncthreads();
    // stage: copy the bin's 8 XCD runs into LDS contiguously
    int tot = 0;
    for (int xc = 0; xc < NXCD; ++xc) {
        int cnt = bcur2[xc * NBIN + bin];
        const unsigned* p = benc2 + ((long long)xc * NBIN + bin) * CAP2X;
        for (int i = tid; i < cnt; i += 256) codes[tot + i] = p[i];
        tot += cnt;
    }
    __syncthreads();
    for (int i = tid; i < tot; i += 256)
        atomicAdd(&hist[codes[i] & 0xFFu], 1);
    __syncthreads();
    int deg = hist[tid];
    int pad = (deg + 7) & ~7;
    scn[tid] = pad;
    __syncthreads();
    for (int off = 1; off < 256; off <<= 1) {
        int v = 0;
        if (tid >= off) v = scn[tid - off];
        __syncthreads();
        if (tid >= off) scn[tid] += v;
        __syncthreads();
    }
    int excl = scn[tid] - pad;               // exclusive scan of padded degs
    int gbase = bin * CAP2R;
    lcur[tid] = gbase + excl;
    if (tid < BIN_N) {
        int n = bin * BIN_N + tid;
        obeg[n] = gbase + excl;
        oend[n] = gbase + excl + pad;
        float dn = rsqrtf((float)(deg + 1));
        dis[n] = dn;
#pragma unroll
        for (int j = 0; j < IN_F; ++j)
            sx[n * 8 + j] = (f16)(x[n * IN_F + j] * dn);
        sx[n * 8 + 6] = (f16)0.0f;
        sx[n * 8 + 7] = (f16)0.0f;
    }
    __syncthreads();
    for (int i = tid; i < tot; i += 256) {
        unsigned c = codes[i];
        int pos = atomicAdd(&lcur[c & 0xFFu], 1);
        csr[pos] = (int)(c >> 8);
    }
    __syncthreads();
    if (tid < BIN_N) {
        int end = gbase + excl + pad;
        for (int j = lcur[tid]; j < end; ++j) csr[j] = N_NODES;   // zero-row pad
    }
}

// ---- fused layer 1: gather(sx dwords, fp16x2 accum, unroll x16) -> h1 -> t2 fp8 ----
// 64 nodes/block, 4 lanes/node; each lane owns one dword (2 fp16 feats).
__global__ void k_l1(const unsigned* __restrict__ sxu, const int* __restrict__ obeg,
                     const int* __restrict__ oend, const int* __restrict__ csr,
                     const float* __restrict__ W1, const float* __restrict__ b1,
                     const float* __restrict__ W2, const float* __restrict__ dis,
                     unsigned* __restrict__ t2) {
    __shared__ float sW1[IN_F * H1];
    __shared__ float sb1[H1];
    __shared__ float sW2[H1 * H2];
    __shared__ float sagg[64][9];       // +pad
    __shared__ float sh1[64][H1 + 1];   // +pad
    __shared__ float sdis[64];
    int tid = threadIdx.x;
    for (int i = tid; i < IN_F * H1; i += 256) sW1[i] = W1[i];
    if (tid < H1) sb1[tid] = b1[tid];
    for (int i = tid; i < H1 * H2; i += 256) sW2[i] = W2[i];
    int loc = tid >> 2;        // 0..63
    int f = tid & 3;           // dword index within 16B sx row
    int n = blockIdx.x * 64 + loc;
    bool ok = n < N_NODES;
    if (ok) {
        h2 acc = uph(sxu[(n << 2) + f]);
        int b = obeg[n], e = oend[n];
        int j = b;
        for (; j + 16 <= e; j += 16) {
            const iv4* p = (const iv4*)(csr + j);
            iv4 ia = p[0], ib = p[1], ic = p[2], id = p[3];
            unsigned w[16];
            w[0]  = sxu[(ia.x << 2) + f]; w[1]  = sxu[(ia.y << 2) + f];
            w[2]  = sxu[(ia.z << 2) + f]; w[3]  = sxu[(ia.w << 2) + f];
            w[4]  = sxu[(ib.x << 2) + f]; w[5]  = sxu[(ib.y << 2) + f];
            w[6]  = sxu[(ib.z << 2) + f]; w[7]  = sxu[(ib.w << 2) + f];
            w[8]  = sxu[(ic.x << 2) + f]; w[9]  = sxu[(ic.y << 2) + f];
            w[10] = sxu[(ic.z << 2) + f]; w[11] = sxu[(ic.w << 2) + f];
            w[12] = sxu[(id.x << 2) + f]; w[13] = sxu[(id.y << 2) + f];
            w[14] = sxu[(id.z << 2) + f]; w[15] = sxu[(id.w << 2) + f];
            h2 s0 = (uph(w[0])  + uph(w[1]))  + (uph(w[2])  + uph(w[3]));
            h2 s1 = (uph(w[4])  + uph(w[5]))  + (uph(w[6])  + uph(w[7]));
            h2 s2 = (uph(w[8])  + uph(w[9]))  + (uph(w[10]) + uph(w[11]));
            h2 s3 = (uph(w[12]) + uph(w[13])) + (uph(w[14]) + uph(w[15]));
            acc += (s0 + s1) + (s2 + s3);
        }
        if (j < e) {   // one remaining 8-chunk (lists are 8-aligned)
            const iv4* p = (const iv4*)(csr + j);
            iv4 ia = p[0], ib = p[1];
            unsigned w[8];
            w[0] = sxu[(ia.x << 2) + f]; w[1] = sxu[(ia.y << 2) + f];
            w[2] = sxu[(ia.z << 2) + f]; w[3] = sxu[(ia.w << 2) + f];
            w[4] = sxu[(ib.x << 2) + f]; w[5] = sxu[(ib.y << 2) + f];
            w[6] = sxu[(ib.z << 2) + f]; w[7] = sxu[(ib.w << 2) + f];
            h2 s0 = (uph(w[0]) + uph(w[1])) + (uph(w[2]) + uph(w[3]));
            h2 s1 = (uph(w[4]) + uph(w[5])) + (uph(w[6]) + uph(w[7]));
            acc += s0 + s1;
        }
        sagg[loc][2*f]   = (float)acc.x;
        sagg[loc][2*f+1] = (float)acc.y;
        if (f == 0) sdis[loc] = dis[n];
    }
    __syncthreads();
    float dn = sdis[loc];
    // stage 2: h1 = lrelu(dis*(agg@W1)+b1); each lane does 16 features
#pragma unroll
    for (int q = 0; q < 16; ++q) {
        int k = (f << 4) + q;
        float s = 0.0f;
#pragma unroll
        for (int j = 0; j < IN_F; ++j) s += sagg[loc][j] * sW1[j * H1 + k];
        sh1[loc][k] = lrelu(s * dn + sb1[k]);
    }
    __syncthreads();
    // stage 3: t2 = dis*(h1@W2); each lane does 8 features -> 2 fp8 dwords
    float r[8];
#pragma unroll
    for (int q = 0; q < 8; ++q) {
        int f2i = (f << 3) + q;
        float s = 0.0f;
#pragma unroll
        for (int k = 0; k < H1; ++k) s += sh1[loc][k] * sW2[k * H2 + f2i];
        r[q] = s * dn;
    }
    if (ok) {
        uint2 pk;
        pk.x = pk8(r[0], r[1], r[2], r[3]);
        pk.y = pk8(r[4], r[5], r[6], r[7]);
        *((uint2*)(t2 + n * 8 + f * 2)) = pk;
    }
}

// ---- layer-2 gather: 8 lanes/node, fp8 dword rows (4 feats/lane) ----
__global__ void k_gather2(const unsigned* __restrict__ t2u, const int* __restrict__ obeg,
                          const int* __restrict__ oend, const int* __restrict__ csr,
                          const float* __restrict__ dis, const float* __restrict__ b2,
                          const int* __restrict__ batch,
                          float* __restrict__ gsum, float* __restrict__ gcnt) {
    __shared__ float sv[32][H2];
    __shared__ int sg[32];
    int idx = blockIdx.x * blockDim.x + threadIdx.x;
    int n = idx >> 3;          // 32 nodes per 256-thread block
    int f = idx & 7;           // dword = features 4f..4f+3
    f2 a01, a23;
    upk8(t2u[(n << 3) + f], a01, a23);
    int b = obeg[n], e = oend[n];
    int j = b;
    for (; j + 16 <= e; j += 16) {
        const iv4* p = (const iv4*)(csr + j);
        iv4 ia = p[0], ib = p[1], ic = p[2], id = p[3];
        unsigned w[16];
        w[0]  = t2u[(ia.x << 3) + f]; w[1]  = t2u[(ia.y << 3) + f];
        w[2]  = t2u[(ia.z << 3) + f]; w[3]  = t2u[(ia.w << 3) + f];
        w[4]  = t2u[(ib.x << 3) + f]; w[5]  = t2u[(ib.y << 3) + f];
        w[6]  = t2u[(ib.z << 3) + f]; w[7]  = t2u[(ib.w << 3) + f];
        w[8]  = t2u[(ic.x << 3) + f]; w[9]  = t2u[(ic.y << 3) + f];
        w[10] = t2u[(ic.z << 3) + f]; w[11] = t2u[(ic.w << 3) + f];
        w[12] = t2u[(id.x << 3) + f]; w[13] = t2u[(id.y << 3) + f];
        w[14] = t2u[(id.z << 3) + f]; w[15] = t2u[(id.w << 3) + f];
#pragma unroll
        for (int q = 0; q < 16; ++q) {
            f2 lo, hi;
            upk8(w[q], lo, hi);
            a01 += lo;
            a23 += hi;
        }
    }
    if (j < e) {   // one remaining 8-chunk (lists are 8-aligned)
        const iv4* p = (const iv4*)(csr + j);
        iv4 ia = p[0], ib = p[1];
        unsigned w[8];
        w[0] = t2u[(ia.x << 3) + f]; w[1] = t2u[(ia.y << 3) + f];
        w[2] = t2u[(ia.z << 3) + f]; w[3] = t2u[(ia.w << 3) + f];
        w[4] = t2u[(ib.x << 3) + f]; w[5] = t2u[(ib.y << 3) + f];
        w[6] = t2u[(ib.z << 3) + f]; w[7] = t2u[(ib.w << 3) + f];
#pragma unroll
        for (int q = 0; q < 8; ++q) {
            f2 lo, hi;
            upk8(w[q], lo, hi);
            a01 += lo;
            a23 += hi;
        }
    }
    float dn = dis[n];
    float v0 = lrelu(a01.x * dn + b2[4*f]);
    float v1 = lrelu(a01.y * dn + b2[4*f+1]);
    float v2 = lrelu(a23.x * dn + b2[4*f+2]);
    float v3 = lrelu(a23.y * dn + b2[4*f+3]);
    int g = batch[n];
    int loc = threadIdx.x >> 3;
    sv[loc][4*f]   = v0;
    sv[loc][4*f+1] = v1;
    sv[loc][4*f+2] = v2;
    sv[loc][4*f+3] = v3;
    if (f == 0) sg[loc] = g;
    __syncthreads();
    bool leader = true;
    for (int l = 0; l < loc; ++l) leader &= (sg[l] != g);
    if (leader) {
        float s0 = v0, s1 = v1, s2 = v2, s3 = v3;
        float c = 1.0f;
        for (int l = loc + 1; l < 32; ++l)
            if (sg[l] == g) {
                s0 += sv[l][4*f];   s1 += sv[l][4*f+1];
                s2 += sv[l][4*f+2]; s3 += sv[l][4*f+3];
                c += 1.0f;
            }
        atomicAdd(&gsum[g * H2 + 4*f],     s0);
        atomicAdd(&gsum[g * H2 + 4*f + 1], s1);
        atomicAdd(&gsum[g * H2 + 4*f + 2], s2);
        atomicAdd(&gsum[g * H2 + 4*f + 3], s3);
        if (f == 0) atomicAdd(&gcnt[g], c);
    }
}

__global__ void k_final(const float* __restrict__ gsum, const float* __restrict__ gcnt,
                        const float* __restrict__ Wlin, const float* __restrict__ blin,
                        float* __restrict__ out) {
    int idx = blockIdx.x * blockDim.x + threadIdx.x;
    if (idx >= N_GRAPHS * 2) return;
    int g = idx >> 1;
    int t = idx & 1;
    float inv = 1.0f / fmaxf(gcnt[g], 1.0f);
    float s = blin[t];
#pragma unroll
    for (int ff = 0; ff < H2; ++ff)
        s += gsum[g * H2 + ff] * inv * Wlin[ff * 2 + t];
    out[idx] = s;
}

static inline int cdiv(long long a, int b) { return (int)((a + b - 1) / b); }

extern "C" void kernel_launch(void* const* d_in, const int* in_sizes, int n_in,
                              void* d_out, int out_size, void* d_ws, size_t ws_size,
                              hipStream_t stream) {
    const float* x    = (const float*)d_in[0];
    const int*   ei   = (const int*)d_in[1];
    const int*   batch= (const int*)d_in[2];
    const float* W1   = (const float*)d_in[3];
    const float* b1   = (const float*)d_in[4];
    const float* W2   = (const float*)d_in[5];
    const float* b2   = (const float*)d_in[6];
    const float* Wlin = (const float*)d_in[7];
    const float* blin = (const float*)d_in[8];
    float* out = (float*)d_out;

    const int* src = ei;
    const int* dst = ei + N_EDGES;

    // ---- workspace layout ----
    unsigned* t2 = (unsigned*)d_ws;                     // 8*(N+1) dwords (fp8 rows)
    f16*   sx   = (f16*)(t2 + 8LL * (N_NODES + 1));     // 8*(N+1) fp16
    float* dis  = (float*)(sx + 8LL * (N_NODES + 1));   // N f32
    float* gsum = dis + N_NODES;                        // 32G
    float* gcnt = gsum + (long long)N_GRAPHS * H2;      // G
    size_t ioff = ((size_t)(gcnt + N_GRAPHS) + 63) & ~(size_t)63;
    int*  bcur2   = (int*)ioff;                         // NXCD*NBIN (+pad)
    int*  obeg    = bcur2 + NXCD * NBIN + 16;           // N
    int*  oend    = obeg + N_NODES;                     // N
    size_t boff = ((size_t)(oend + N_NODES) + 63) & ~(size_t)63;
    unsigned* benc2 = (unsigned*)boff;                  // NXCD*NBIN*CAP2X
    int*  csr      = (int*)(benc2 + (long long)NXCD * NBIN * CAP2X);  // NBIN*CAP2R

    const int B = 256;

    k_init<<<cdiv(N_GRAPHS * H2 + N_GRAPHS, B), B, 0, stream>>>(
        gsum, bcur2, t2 + 8LL * N_NODES, sx + 8LL * N_NODES);

    k_bin400<<<NSEGB, B, 0, stream>>>(src, dst, bcur2, benc2);
    k_sort<<<NBIN, B, 0, stream>>>(benc2, bcur2, x, csr, obeg, oend, dis, sx);

    k_l1<<<cdiv(N_NODES, 64), B, 0, stream>>>((const unsigned*)sx, obeg, oend, csr,
                                              W1, b1, W2, dis, t2);
    k_gather2<<<cdiv((long long)N_NODES * 8, B), B, 0, stream>>>(
        (const unsigned*)t2, obeg, oend, csr, dis, b2, batch, gsum, gcnt);
    k_final<<<cdiv(N_GRAPHS * 2, B), B, 0, stream>>>(gsum, gcnt, Wlin, blin, out);
}